// Round 2
// baseline (136.299 us; speedup 1.0000x reference)
//
#include <hip/hip_runtime.h>
#include <math.h>

#define DK 32
#define OUT_DIM 32

typedef float    f32x4 __attribute__((ext_vector_type(4)));
typedef _Float16 h2    __attribute__((ext_vector_type(2)));
typedef _Float16 h8    __attribute__((ext_vector_type(8)));

#if __has_builtin(__builtin_amdgcn_fdot2)
#define FDOT2(a, b, c) __builtin_amdgcn_fdot2((a), (b), (c), false)
#else
#define FDOT2(a, b, c) ((c) + (float)(a).x * (float)(b).x + (float)(a).y * (float)(b).y)
#endif

#if __has_builtin(__builtin_amdgcn_exp2f)
#define EXP2F(x) __builtin_amdgcn_exp2f(x)
#else
#define EXP2F(x) exp2f(x)
#endif

__device__ __forceinline__ h2 as_h2(unsigned u) {
    union { unsigned u; h2 h; } v; v.u = u; return v.h;
}
__device__ __forceinline__ unsigned as_u32(h2 h) {
    union { unsigned u; h2 h; } v; v.h = h; return v.u;
}
__device__ __forceinline__ h2 shfl_xor_h2(h2 v, int m) {
    union { unsigned u; h2 h; } x; x.h = v;
    x.u = (unsigned)__shfl_xor((int)x.u, m);
    return x.h;
}

// R13 prep: int4-vectorized dst boundary scan (4 edges/thread) + the R12
// uint4 KV pack (one thread per node-chunk). KVH chunk c of node s =
// {K01,K23,V01,V23} f16 pairs for dims 4c..4c+3.
__global__ void prep_kernel(const int* __restrict__ dst,
                            const float4* __restrict__ K4,
                            const float4* __restrict__ V4,
                            int E, int N,
                            int* __restrict__ row_ptr,
                            uint4* __restrict__ KVH) {
    const int t  = blockIdx.x * blockDim.x + threadIdx.x;
    const int e0 = t * 4;
    if (e0 < E) {
        int cur[4];
        if (e0 + 4 <= E) {
            const int4 dd = *(const int4*)(dst + e0);
            cur[0] = dd.x; cur[1] = dd.y; cur[2] = dd.z; cur[3] = dd.w;
        } else {
#pragma unroll
            for (int k = 0; k < 4; ++k)
                cur[k] = (e0 + k < E) ? dst[e0 + k] : 0;
        }
        int prev = (e0 == 0) ? -1 : dst[e0 - 1];
#pragma unroll
        for (int k = 0; k < 4; ++k) {
            const int ee = e0 + k;
            if (ee < E) {
                for (int j = prev + 1; j <= cur[k]; ++j) row_ptr[j] = ee;
                if (ee == E - 1)
                    for (int j = cur[k] + 1; j <= N; ++j) row_ptr[j] = E;
                prev = cur[k];
            }
        }
    }
    if (t < N * 8) {
        const float4 kf = K4[t];
        const float4 vf = V4[t];
        h2 k01, k23, v01, v23;
        k01.x = (_Float16)kf.x;  k01.y = (_Float16)kf.y;
        k23.x = (_Float16)kf.z;  k23.y = (_Float16)kf.w;
        v01.x = (_Float16)vf.x;  v01.y = (_Float16)vf.y;
        v23.x = (_Float16)vf.z;  v23.y = (_Float16)vf.w;
        uint4 o;
        o.x = as_u32(k01); o.y = as_u32(k23); o.z = as_u32(v01); o.w = as_u32(v23);
        KVH[t] = o;
    }
}

// Fallback-path row_ptr builder (ws too small for KV).
__global__ void build_row_ptr_kernel(const int* __restrict__ dst, int E, int N,
                                     int* __restrict__ row_ptr) {
    int e = blockIdx.x * blockDim.x + threadIdx.x;
    if (e >= E) return;
    int cur  = dst[e];
    int prev = (e == 0) ? -1 : dst[e - 1];
    for (int j = prev + 1; j <= cur; ++j) row_ptr[j] = e;
    if (e == E - 1) {
        for (int j = cur + 1; j <= N; ++j) row_ptr[j] = E;
    }
}

// R13: single lockstep loop over ALL 4 wave-nodes (8 edge slots each per
// step, 32 slots/step = same VALU as R12's pair-step) + depth-3 rotating
// KV prefetch with unconditional CLAMPED loads.
// Post-mortem of R12: VALUBusy 43% at 3.25 waves/SIMD -> per-wave duty 13%;
// segments avg ~1-2 batches so the 2-deep pipeline had no steady state and
// the serial src->KV prologue chain ran TWICE per wave (pr=0,1). Here it
// runs once, and because every load is index-clamped (finished segments
// re-read their cap line -> L1 hit, weight masked to 0), prefetch needs no
// validity bookkeeping: prologue issues src@{0,8,16,24}+KV@{0,8,16}; phase
// k consumes batch t, refills its buffer with batch t+3 using src fetched
// one phase earlier, exits on one scalar flag. After the single prologue
// chain every KV gather is in flight concurrently.
// exp: q pre-scaled by log2(e)/32 so softmax weight = v_exp_f32 (2^x).
__global__ __launch_bounds__(256) void gat_fused_kernel(
    const float* __restrict__ X, const uint4* __restrict__ KV,
    const float* __restrict__ Wo, const float* __restrict__ bo,
    const int* __restrict__ src, const int* __restrict__ row_ptr,
    float* __restrict__ out, int N) {

    __shared__ uint4 s_part[16 * 17];   // block A-tile, row stride 17 (pad->b128)

    const int tid  = threadIdx.x;
    const int w    = tid >> 6;    // wave 0..3
    const int lane = tid & 63;
    const int g    = lane >> 3;   // edge slot 0..7
    const int c    = lane & 7;    // dim chunk 0..7

    const int n_blk = blockIdx.x * 16;       // block's first node
    const int n_w   = n_blk + w * 4;         // wave's first node

    // row_ptr[n_w .. n_w+4] into lanes 0..4 (clamped; row_ptr[N] = E)
    const int rpv = row_ptr[min(n_w + min(lane, 4), N)];

    const float4* X4 = (const float4*)X;
    unsigned* part32 = (unsigned*)s_part;
    const float scale = 0.03125f * 1.44269504f;  // 1/dk, log2(e) folded for exp2

    int beg[4], en[4], cap[4], e[4];
#pragma unroll
    for (int i = 0; i < 4; ++i) {
        beg[i] = __builtin_amdgcn_readlane(rpv, i);
        en[i]  = __builtin_amdgcn_readlane(rpv, i + 1);
        cap[i] = max(en[i] - 1, 0);   // safe clamp (empty -> idx 0)
        e[i]   = beg[i];
    }

    h2 q01[4], q23[4];
#pragma unroll
    for (int i = 0; i < 4; ++i) {
        const float4 qf = X4[min(n_w + i, N - 1) * 8 + c];
        q01[i].x = (_Float16)(qf.x * scale);
        q01[i].y = (_Float16)(qf.y * scale);
        q23[i].x = (_Float16)(qf.z * scale);
        q23[i].y = (_Float16)(qf.w * scale);
    }

    float l[4] = {0.0f, 0.0f, 0.0f, 0.0f};
    h2 a01[4], a23[4];
#pragma unroll
    for (int i = 0; i < 4; ++i) { a01[i] = (h2)0; a23[i] = (h2)0; }

    // clamped src indices for batch at edge-offset o from current e
    auto ldsrc = [&](int o, int* s) {
#pragma unroll
        for (int i = 0; i < 4; ++i) s[i] = src[min(e[i] + o + g, cap[i])];
    };
    auto ldkv = [&](const int* s, uint4* B) {
#pragma unroll
        for (int i = 0; i < 4; ++i) B[i] = KV[s[i] * 8 + c];
    };
    // one batch: 8 edges per node, masks from CURRENT e
    auto step = [&](const uint4* B) {
        float p[4];
#pragma unroll
        for (int i = 0; i < 4; ++i)
            p[i] = FDOT2(as_h2(B[i].y), q23[i], FDOT2(as_h2(B[i].x), q01[i], 0.0f));
#pragma unroll
        for (int i = 0; i < 4; ++i) p[i] += __shfl_xor(p[i], 1);
#pragma unroll
        for (int i = 0; i < 4; ++i) p[i] += __shfl_xor(p[i], 2);
#pragma unroll
        for (int i = 0; i < 4; ++i) p[i] += __shfl_xor(p[i], 4);
#pragma unroll
        for (int i = 0; i < 4; ++i) {
            const float wt = (e[i] + g < en[i]) ? EXP2F(p[i]) : 0.0f;
            l[i] += wt;
            h2 wh; wh.x = (_Float16)wt; wh.y = wh.x;
            a01[i] += wh * as_h2(B[i].z);
            a23[i] += wh * as_h2(B[i].w);
        }
    };
    auto nexists = [&]() {   // does the batch AFTER the current one exist?
        return (e[0] + 8 < en[0]) || (e[1] + 8 < en[1]) ||
               (e[2] + 8 < en[2]) || (e[3] + 8 < en[3]);
    };
    auto adv = [&]() {
#pragma unroll
        for (int i = 0; i < 4; ++i) e[i] += 8;
    };

    const bool any0 = (e[0] < en[0]) || (e[1] < en[1]) ||
                      (e[2] < en[2]) || (e[3] < en[3]);
    if (any0) {
        int s0[4], s1[4], s2[4], sCA[4], sAB[4], sBC[4];
        uint4 B0[4], B1[4], B2[4];
        // prologue: all src first (8 independent dwords/lane), then gathers
        ldsrc(0, s0);  ldsrc(8, s1);  ldsrc(16, s2);  ldsrc(24, sCA);
        ldkv(s0, B0);  ldkv(s1, B1);  ldkv(s2, B2);

        for (;;) {
            // phase A: consume B0 @ t; refill B0 <- t+3; src -> t+4
            bool mn = nexists();
            step(B0);
            ldkv(sCA, B0);
            ldsrc(32, sAB);
            adv();
            if (!mn) break;
            // phase B
            mn = nexists();
            step(B1);
            ldkv(sAB, B1);
            ldsrc(32, sBC);
            adv();
            if (!mn) break;
            // phase C
            mn = nexists();
            step(B2);
            ldkv(sBC, B2);
            ldsrc(32, sCA);
            adv();
            if (!mn) break;
        }
    }

    // ---- per-node reductions + A-tile writes ----
#pragma unroll
    for (int i = 0; i < 4; ++i) {
        l[i]   += __shfl_xor(l[i], 8);
        a01[i] += shfl_xor_h2(a01[i], 8);
        a23[i] += shfl_xor_h2(a23[i], 8);
        l[i] += __shfl_xor(l[i], 16);
        l[i] += __shfl_xor(l[i], 32);
        const float inv = (en[i] > beg[i]) ? (1.0f / l[i]) : 0.0f;
        h2 iv; iv.x = (_Float16)inv; iv.y = iv.x;
        a01[i] *= iv;  a23[i] *= iv;
    }

    if ((g & 1) == 0) {                  // even groups hold pair sums
        const int p = g >> 1;
#pragma unroll
        for (int i = 0; i < 4; ++i) {
            const int off = (w * 4 + i) * 68 + p * 16 + c * 2;  // uint32 units
            part32[off]     = as_u32(a01[i]);
            part32[off + 1] = as_u32(a23[i]);
        }
    }

    __syncthreads();

    // wave 0: projection + partial-group reduction for the block's 16 nodes
    if (w == 0) {
        const int quad = lane >> 4;   // 0..3
        const int col  = lane & 15;

        union BF { h8 v; _Float16 u[8]; };
        BF bf0, bf1;
#pragma unroll
        for (int j2 = 0; j2 < 8; ++j2) {
            bf0.u[j2] = (_Float16)Wo[(quad * 8 + j2) * OUT_DIM + col];
            bf1.u[j2] = (_Float16)Wo[(quad * 8 + j2) * OUT_DIM + 16 + col];
        }
        const float bias0 = bo[col];
        const float bias1 = bo[16 + col];

        union AF { uint4 u; h8 v; };
        f32x4 C0 = {bias0, bias0, bias0, bias0};
        f32x4 C1 = {bias1, bias1, bias1, bias1};
#pragma unroll
        for (int cc = 0; cc < 4; ++cc) {
            AF a;
            a.u = s_part[col * 17 + cc * 4 + quad];      // ds_read_b128
            C0 = __builtin_amdgcn_mfma_f32_16x16x32_f16(a.v, bf0.v, C0, 0, 0, 0);
            C1 = __builtin_amdgcn_mfma_f32_16x16x32_f16(a.v, bf1.v, C1, 0, 0, 0);
        }
        // C/D layout: col = lane&15, row = quad*4 + reg (verified mapping)
#pragma unroll
        for (int r = 0; r < 4; ++r) {
            const int n = n_blk + quad * 4 + r;
            if (n < N) {
                out[n * OUT_DIM + col]      = C0[r];
                out[n * OUT_DIM + 16 + col] = C1[r];
            }
        }
    }
}

// ---- fallback (R4-proven fp32 path, used only if ws too small for KV) ----
__global__ __launch_bounds__(256) void gat_node_f32_kernel(
    const float* __restrict__ X, const float* __restrict__ Km,
    const float* __restrict__ Vm, const float* __restrict__ Wo,
    const float* __restrict__ bo, const int* __restrict__ src,
    const int* __restrict__ row_ptr, float* __restrict__ out, int N) {
    const int tid  = threadIdx.x;
    const int wave = tid >> 6;
    const int lane = tid & 63;
    const int g    = lane >> 3;
    const int c    = lane & 7;
    const int j    = lane & 31;
    const int half = lane >> 5;
    const int n = blockIdx.x * 4 + wave;
    if (n >= N) return;
    const int begin = row_ptr[n];
    const int end   = row_ptr[n + 1];
    const float4* X4 = (const float4*)X;
    const float4* K4 = (const float4*)Km;
    const float4* V4 = (const float4*)Vm;
    const float4 q4 = X4[n * 8 + c];
    float  l   = 0.0f;
    float4 acc = make_float4(0.0f, 0.0f, 0.0f, 0.0f);
    for (int e0 = begin; e0 < end; e0 += 16) {
        const int  ea = e0 + g;
        const int  eb = ea + 8;
        const bool va = ea < end;
        const bool vb = eb < end;
        const int sa = src[min(ea, end - 1)];
        const int sb = src[min(eb, end - 1)];
        const float4 ka  = K4[sa * 8 + c];
        const float4 kb  = K4[sb * 8 + c];
        const float4 vva = V4[sa * 8 + c];
        const float4 vvb = V4[sb * 8 + c];
        float pa = fmaf(ka.x, q4.x, fmaf(ka.y, q4.y, fmaf(ka.z, q4.z, ka.w * q4.w)));
        float pb = fmaf(kb.x, q4.x, fmaf(kb.y, q4.y, fmaf(kb.z, q4.z, kb.w * q4.w)));
        pa += __shfl_xor(pa, 1);  pb += __shfl_xor(pb, 1);
        pa += __shfl_xor(pa, 2);  pb += __shfl_xor(pb, 2);
        pa += __shfl_xor(pa, 4);  pb += __shfl_xor(pb, 4);
        const float wa = va ? __expf(pa * 0.03125f) : 0.0f;
        const float wb = vb ? __expf(pb * 0.03125f) : 0.0f;
        l += wa + wb;
        acc.x = fmaf(wa, vva.x, acc.x);  acc.y = fmaf(wa, vva.y, acc.y);
        acc.z = fmaf(wa, vva.z, acc.z);  acc.w = fmaf(wa, vva.w, acc.w);
        acc.x = fmaf(wb, vvb.x, acc.x);  acc.y = fmaf(wb, vvb.y, acc.y);
        acc.z = fmaf(wb, vvb.z, acc.z);  acc.w = fmaf(wb, vvb.w, acc.w);
    }
#pragma unroll
    for (int m = 8; m <= 32; m <<= 1) {
        l     += __shfl_xor(l, m);
        acc.x += __shfl_xor(acc.x, m);
        acc.y += __shfl_xor(acc.y, m);
        acc.z += __shfl_xor(acc.z, m);
        acc.w += __shfl_xor(acc.w, m);
    }
    const float inv = (end > begin) ? (1.0f / l) : 0.0f;
    float ag[4] = {acc.x, acc.y, acc.z, acc.w};
    float s = 0.0f;
#pragma unroll
    for (int k = 0; k < 32; ++k) {
        const float a = __int_as_float(
            __builtin_amdgcn_readlane(__float_as_int(ag[k & 3]), k >> 2));
        s = fmaf(a, Wo[k * OUT_DIM + j], s);
    }
    if (half == 0) {
        out[n * OUT_DIM + j] = fmaf(s, inv, bo[j]);
    }
}

extern "C" void kernel_launch(void* const* d_in, const int* in_sizes, int n_in,
                              void* d_out, int out_size, void* d_ws, size_t ws_size,
                              hipStream_t stream) {
    const float* X  = (const float*)d_in[0];
    const float* Km = (const float*)d_in[1];
    const float* Vm = (const float*)d_in[2];
    const float* Wo = (const float*)d_in[3];
    const float* bo = (const float*)d_in[4];
    const int* src  = (const int*)d_in[5];
    const int* dst  = (const int*)d_in[6];

    const int N = in_sizes[0] / DK;
    const int E = in_sizes[5];

    int* row_ptr = (int*)d_ws;                              // (N+1) ints
    const size_t kv_off = (((size_t)(N + 1) * 4) + 127) & ~(size_t)127;
    unsigned* KV = (unsigned*)((char*)d_ws + kv_off);       // N*DK uint32
    const size_t need = kv_off + (size_t)N * DK * 4;
    float* out = (float*)d_out;

    const int tb = 256;

    if (ws_size >= need) {
        const int nE4   = (E + 3) / 4;       // 4 edges per thread (dst scan)
        const int total = N * 8;             // one thread per uint4 (KV pack)
        const int prep_n = (nE4 > total) ? nE4 : total;
        prep_kernel<<<(prep_n + tb - 1) / tb, tb, 0, stream>>>(
            dst, (const float4*)Km, (const float4*)Vm, E, N,
            row_ptr, (uint4*)KV);
        const int grid = (N + 15) / 16;     // 16 nodes per block, 4 per wave
        gat_fused_kernel<<<grid, 256, 0, stream>>>(X, (const uint4*)KV, Wo, bo,
                                                   src, row_ptr, out, N);
    } else {
        build_row_ptr_kernel<<<(E + tb - 1) / tb, tb, 0, stream>>>(dst, E, N, row_ptr);
        const int grid = (N + 3) / 4;
        gat_node_f32_kernel<<<grid, 256, 0, stream>>>(X, Km, Vm, Wo, bo,
                                                      src, row_ptr, out, N);
    }
}